// Round 6
// baseline (343.909 us; speedup 1.0000x reference)
//
#include <hip/hip_runtime.h>
#include <math.h>

#define N_TOK 16384
#define DIM   768
#define FFD   3072
#define NEXP  8
#define EPSV  1e-6f

typedef __attribute__((ext_vector_type(4))) float f32x4;
typedef __attribute__((ext_vector_type(4))) unsigned short u16x4;
typedef __attribute__((ext_vector_type(8))) unsigned short u16x8;
typedef __attribute__((ext_vector_type(8))) __bf16 bf16x8;

static __device__ __forceinline__ unsigned short f2bf(float f) {
    unsigned int u = __builtin_bit_cast(unsigned int, f);
    u += 0x7fffu + ((u >> 16) & 1u);   // round-to-nearest-even
    return (unsigned short)(u >> 16);
}
static __device__ __forceinline__ bf16x8 as_bf(u16x8 v) {
    return __builtin_bit_cast(bf16x8, v);
}
static __device__ __forceinline__ void gload16(const void* g, void* l) {
    __builtin_amdgcn_global_load_lds(
        (const __attribute__((address_space(1))) unsigned int*)g,
        (__attribute__((address_space(3))) unsigned int*)l, 16, 0, 0);
}

// ---------------------------------------------------------------------------
// Kernel 0: convert+transpose  in[e][R][C] f32  ->  out[e][C][R] bf16
// ---------------------------------------------------------------------------
__global__ __launch_bounds__(256) void k_convT(
    const float* __restrict__ in, unsigned short* __restrict__ outp,
    int R, int C)
{
    __shared__ float tile[64][68];
    const int bc = C >> 6, br = R >> 6;
    const int b = blockIdx.x;
    const int e = b / (bc * br);
    const int rem = b - e * bc * br;
    const int rt = rem / bc, ct = rem - rt * bc;
    const int t = threadIdx.x;
    {
        const int r = t >> 2, c4 = (t & 3) << 4;
        const float* src = in + ((size_t)e * R + rt * 64 + r) * C + ct * 64 + c4;
#pragma unroll
        for (int q = 0; q < 4; q++) {
            float4 f = ((const float4*)src)[q];
            tile[r][c4 + q * 4 + 0] = f.x;
            tile[r][c4 + q * 4 + 1] = f.y;
            tile[r][c4 + q * 4 + 2] = f.z;
            tile[r][c4 + q * 4 + 3] = f.w;
        }
    }
    __syncthreads();
    {
        const int c = t >> 2, r4 = (t & 3) << 4;
        u16x8 o0, o1;
#pragma unroll
        for (int j = 0; j < 8; j++)  o0[j] = f2bf(tile[r4 + j][c]);
#pragma unroll
        for (int j = 0; j < 8; j++)  o1[j] = f2bf(tile[r4 + 8 + j][c]);
        unsigned short* dst = outp + ((size_t)e * C + ct * 64 + c) * R + rt * 64 + r4;
        *(u16x8*)dst       = o0;
        *(u16x8*)(dst + 8) = o1;
    }
}

// ---------------------------------------------------------------------------
// Kernel 1: RMSNorm + router, one wave per token. NO global atomics.
// ---------------------------------------------------------------------------
__global__ __launch_bounds__(256) void k_router(
    const float* __restrict__ x, const float* __restrict__ lnw,
    const float* __restrict__ rw,
    float* __restrict__ out_logits, float* __restrict__ out_eidx,
    float* __restrict__ topp, int* __restrict__ eidx,
    unsigned short* __restrict__ xn)
{
    const int wid = threadIdx.x >> 6, lane = threadIdx.x & 63;
    const int tok = blockIdx.x * 4 + wid;
    const size_t base = (size_t)tok * DIM;

    float4 v[3];
#pragma unroll
    for (int j = 0; j < 3; j++)
        v[j] = *(const float4*)(x + base + lane * 4 + j * 256);
    float ss = 0.f;
#pragma unroll
    for (int j = 0; j < 3; j++)
        ss += v[j].x * v[j].x + v[j].y * v[j].y + v[j].z * v[j].z + v[j].w * v[j].w;
#pragma unroll
    for (int s = 32; s > 0; s >>= 1) ss += __shfl_xor(ss, s);
    const float rstd = rsqrtf(ss * (1.0f / DIM) + EPSV);

    float rp[8];
#pragma unroll
    for (int e = 0; e < 8; e++) rp[e] = 0.f;
#pragma unroll
    for (int j = 0; j < 3; j++) {
        float4 lw = *(const float4*)(lnw + lane * 4 + j * 256);
        float xv[4] = { v[j].x * rstd * lw.x, v[j].y * rstd * lw.y,
                        v[j].z * rstd * lw.z, v[j].w * rstd * lw.w };
        u16x4 pk = { f2bf(xv[0]), f2bf(xv[1]), f2bf(xv[2]), f2bf(xv[3]) };
        *(u16x4*)(xn + base + lane * 4 + j * 256) = pk;
#pragma unroll
        for (int i = 0; i < 4; i++) {
            const int d = lane * 4 + j * 256 + i;
            const float4* rr = (const float4*)(rw + (size_t)d * 8);
            float4 a = rr[0], bq = rr[1];
            rp[0] += xv[i] * a.x;  rp[1] += xv[i] * a.y;
            rp[2] += xv[i] * a.z;  rp[3] += xv[i] * a.w;
            rp[4] += xv[i] * bq.x; rp[5] += xv[i] * bq.y;
            rp[6] += xv[i] * bq.z; rp[7] += xv[i] * bq.w;
        }
    }
#pragma unroll
    for (int s = 32; s > 0; s >>= 1) {
#pragma unroll
        for (int e = 0; e < 8; e++) rp[e] += __shfl_xor(rp[e], s);
    }
    if (lane == 0) {
        float m = -1e30f; int am = 0;
#pragma unroll
        for (int e = 0; e < 8; e++) {
            out_logits[(size_t)tok * 8 + e] = rp[e];
            if (rp[e] > m) { m = rp[e]; am = e; }
        }
        float se = 0.f;
#pragma unroll
        for (int e = 0; e < 8; e++) se += expf(rp[e] - m);
        topp[tok] = 1.0f / se;
        out_eidx[tok] = (float)am;
        eidx[tok] = am;
    }
}

// ---------------------------------------------------------------------------
// Kernel 2a: per-block expert histogram (64 blocks x 256 tokens).
// ---------------------------------------------------------------------------
__global__ __launch_bounds__(256) void k_hist(
    const int* __restrict__ eidx, int* __restrict__ blkhist)
{
    __shared__ int h[8];
    if (threadIdx.x < 8) h[threadIdx.x] = 0;
    __syncthreads();
    atomicAdd(&h[eidx[blockIdx.x * 256 + threadIdx.x]], 1);
    __syncthreads();
    if (threadIdx.x < 8) blkhist[blockIdx.x * 8 + threadIdx.x] = h[threadIdx.x];
}

// ---------------------------------------------------------------------------
// Kernel 2b: one-block prefix over the 64x8 histogram.
// ---------------------------------------------------------------------------
__global__ __launch_bounds__(512) void k_prefix(
    const int* __restrict__ blkhist, int* __restrict__ base,
    int* __restrict__ cnt)
{
    __shared__ int h[64 * 8];
    __shared__ int tot[8];
    __shared__ int eb[8];
    const int t = threadIdx.x;
    h[t] = blkhist[t];
    __syncthreads();
    const int b = t >> 3, e = t & 7;
    int s = 0;
    for (int bb = 0; bb < b; bb++) s += h[bb * 8 + e];
    if (b == 63) tot[e] = s + h[63 * 8 + e];
    __syncthreads();
    if (t == 0) {
        int p = 0;
#pragma unroll
        for (int q = 0; q < 8; q++) { eb[q] = p; p += tot[q]; }
    }
    __syncthreads();
    base[t] = eb[e] + s;
    if (t < 8) cnt[t] = tot[t];
}

// ---------------------------------------------------------------------------
// Kernel 2c: deterministic stable scatter using precomputed bases.
// ---------------------------------------------------------------------------
__global__ __launch_bounds__(256) void k_scatter(
    const int* __restrict__ eidx, const int* __restrict__ base,
    int* __restrict__ list)
{
    __shared__ int wcnt[4][8];
    __shared__ int bb[8];
    const int t = threadIdx.x, b = blockIdx.x;
    const int lane = t & 63, wid = t >> 6;
    if (t < 8) bb[t] = base[b * 8 + t];
    const int tok = b * 256 + t;
    const int e = eidx[tok];
    int wrank = 0;
#pragma unroll
    for (int q = 0; q < 8; q++) {
        unsigned long long m = __ballot(e == q);
        if (e == q) wrank = __popcll(m & ((1ull << lane) - 1ull));
        if (lane == 0) wcnt[wid][q] = __popcll(m);
    }
    __syncthreads();
    int wbase = 0;
#pragma unroll
    for (int w = 0; w < 4; w++)
        if (w < wid) wbase += wcnt[w][e];
    list[bb[e] + wbase + wrank] = tok;
}

// ---------------------------------------------------------------------------
// GEMM1: 128x256 tile, BK=64, single-buffer 2-barrier (R3-proven structure),
// A gathered via token list, H written in dense (permuted) row order.
// ---------------------------------------------------------------------------
__global__ __launch_bounds__(256, 2) void k_gemm1(
    const unsigned short* __restrict__ A, const unsigned short* __restrict__ Bw,
    const int* __restrict__ list, const int* __restrict__ cnt,
    unsigned short* __restrict__ Hout)
{
    constexpr int K   = DIM;
    constexpr int N   = FFD;
    constexpr int TNT = N / 256;                  // 12
    __shared__ unsigned short Asm[128 * 64];      // 16 KB
    __shared__ unsigned short Bsm[256 * 64];      // 32 KB
    __shared__ int tokrow[128];
    __shared__ int spref[9];
    __shared__ int ebase[8];

    const int t = threadIdx.x, lane = t & 63, wid = t >> 6;
    if (t == 0) {
        int p = 0, qq = 0;
        spref[0] = 0;
#pragma unroll
        for (int e = 0; e < 8; e++) {
            ebase[e] = qq; qq += cnt[e];
            p += (cnt[e] + 127) >> 7;
            spref[e + 1] = p;
        }
    }
    __syncthreads();
    const int total = spref[8] * TNT;
    const int moff = (wid >> 1) * 64, noff = (wid & 1) * 128;
    const int lr = lane & 15, lq = lane >> 4;

    const int nwg = gridDim.x;
    const int xcd = blockIdx.x & 7, rr8 = blockIdx.x >> 3;
    const int qd = nwg >> 3, rm = nwg & 7;
    const int bid = (xcd < rm ? xcd * (qd + 1) : rm * (qd + 1) + (xcd - rm) * qd) + rr8;

    int arow[4], asub[4], brow[8], bsub[8];
#pragma unroll
    for (int i = 0; i < 4; i++) {
        int c = (wid * 4 + i) * 64 + lane;
        arow[i] = c >> 3;
        asub[i] = (c & 7) ^ (arow[i] & 7);
    }
#pragma unroll
    for (int i = 0; i < 8; i++) {
        int c = (wid * 8 + i) * 64 + lane;
        brow[i] = c >> 3;
        bsub[i] = (c & 7) ^ (brow[i] & 7);
    }

    for (int w = bid; w < total; w += gridDim.x) {
        const int gm = w / TNT, tn = w - gm * TNT;
        int e = 0;
        while (gm >= spref[e + 1]) e++;
        const int ce = cnt[e], eb = ebase[e];
        const int m0 = (gm - spref[e]) * 128, n0 = tn * 256;

        __syncthreads();
        if (t < 128)
            tokrow[t] = (m0 + t < ce) ? list[eb + m0 + t] : list[eb];
        __syncthreads();

        const unsigned short* aP[4];
        const unsigned short* bP[8];
#pragma unroll
        for (int i = 0; i < 4; i++)
            aP[i] = A + (size_t)tokrow[arow[i]] * K + asub[i] * 8;
#pragma unroll
        for (int i = 0; i < 8; i++)
            bP[i] = Bw + ((size_t)e * N + n0 + brow[i]) * K + bsub[i] * 8;

        f32x4 acc[4][8];
#pragma unroll
        for (int mi = 0; mi < 4; mi++)
#pragma unroll
            for (int ni = 0; ni < 8; ni++) acc[mi][ni] = (f32x4){0, 0, 0, 0};

        for (int k0 = 0; k0 < K; k0 += 64) {
#pragma unroll
            for (int i = 0; i < 4; i++)
                gload16(aP[i] + k0, Asm + (wid * 4 + i) * 512);
#pragma unroll
            for (int i = 0; i < 8; i++)
                gload16(bP[i] + k0, Bsm + (wid * 8 + i) * 512);
            __syncthreads();
#pragma unroll
            for (int kf = 0; kf < 2; kf++) {
                const int phys = ((kf * 4 + lq) ^ (lr & 7)) * 8;
                bf16x8 af[4], bfr[8];
#pragma unroll
                for (int mi = 0; mi < 4; mi++)
                    af[mi] = as_bf(*(const u16x8*)&Asm[(moff + mi * 16 + lr) * 64 + phys]);
#pragma unroll
                for (int ni = 0; ni < 8; ni++)
                    bfr[ni] = as_bf(*(const u16x8*)&Bsm[(noff + ni * 16 + lr) * 64 + phys]);
#pragma unroll
                for (int mi = 0; mi < 4; mi++)
#pragma unroll
                    for (int ni = 0; ni < 8; ni++)
                        acc[mi][ni] = __builtin_amdgcn_mfma_f32_16x16x32_bf16(
                            af[mi], bfr[ni], acc[mi][ni], 0, 0, 0);
            }
            __syncthreads();
        }

#pragma unroll
        for (int mi = 0; mi < 4; mi++) {
#pragma unroll
            for (int r4 = 0; r4 < 4; r4++) {
                const int row = moff + mi * 16 + lq * 4 + r4;
                if (m0 + row < ce) {
                    unsigned short* hp = Hout + (size_t)(eb + m0 + row) * FFD + n0 + noff;
#pragma unroll
                    for (int ni = 0; ni < 8; ni++) {
                        float v = acc[mi][ni][r4];
                        v = v > 0.f ? v : 0.f;
                        hp[ni * 16 + lr] = f2bf(v);
                    }
                }
            }
        }
    }
}

// ---------------------------------------------------------------------------
// GEMM2: 64x256 tile, BK=64, single-buffer 2-barrier, dense A rows from
// permuted H. 768 tiles -> 3 blocks/CU (fixes the 384-tile starvation of
// the 128x256 version).
// out[tok,:] = hs[tok,:] + topp[tok]*(Hperm[denserow,:] @ WoT)
// ---------------------------------------------------------------------------
__global__ __launch_bounds__(256, 3) void k_gemm2(
    const unsigned short* __restrict__ A, const unsigned short* __restrict__ Bw,
    const int* __restrict__ list, const int* __restrict__ cnt,
    const float* __restrict__ hs, const float* __restrict__ topp,
    float* __restrict__ out)
{
    constexpr int K   = FFD;
    constexpr int N   = DIM;
    constexpr int TNT = N / 256;                  // 3
    __shared__ unsigned short Asm[64 * 64];       // 8 KB
    __shared__ unsigned short Bsm[256 * 64];      // 32 KB
    __shared__ int tokrow[64];
    __shared__ int spref[9];
    __shared__ int ebase[8];

    const int t = threadIdx.x, lane = t & 63, wid = t >> 6;
    if (t == 0) {
        int p = 0, qq = 0;
        spref[0] = 0;
#pragma unroll
        for (int e = 0; e < 8; e++) {
            ebase[e] = qq; qq += cnt[e];
            p += (cnt[e] + 63) >> 6;
            spref[e + 1] = p;
        }
    }
    __syncthreads();
    const int total = spref[8] * TNT;
    const int moff = (wid >> 1) * 32, noff = (wid & 1) * 128;
    const int lr = lane & 15, lq = lane >> 4;

    const int nwg = gridDim.x;
    const int xcd = blockIdx.x & 7, rr8 = blockIdx.x >> 3;
    const int qd = nwg >> 3, rm = nwg & 7;
    const int bid = (xcd < rm ? xcd * (qd + 1) : rm * (qd + 1) + (xcd - rm) * qd) + rr8;

    int arow[2], asub[2], brow[8], bsub[8];
#pragma unroll
    for (int i = 0; i < 2; i++) {
        int c = (wid * 2 + i) * 64 + lane;         // 0..511
        arow[i] = c >> 3;
        asub[i] = (c & 7) ^ (arow[i] & 7);
    }
#pragma unroll
    for (int i = 0; i < 8; i++) {
        int c = (wid * 8 + i) * 64 + lane;
        brow[i] = c >> 3;
        bsub[i] = (c & 7) ^ (brow[i] & 7);
    }

    for (int w = bid; w < total; w += gridDim.x) {
        const int gm = w / TNT, tn = w - gm * TNT;
        int e = 0;
        while (gm >= spref[e + 1]) e++;
        const int ce = cnt[e], eb = ebase[e];
        const int m0 = (gm - spref[e]) * 64, n0 = tn * 256;

        __syncthreads();
        if (t < 64)
            tokrow[t] = (m0 + t < ce) ? list[eb + m0 + t] : list[eb];
        __syncthreads();

        const unsigned short* aP[2];
        const unsigned short* bP[8];
#pragma unroll
        for (int i = 0; i < 2; i++) {
            const int drow = (m0 + arow[i] < ce) ? (m0 + arow[i]) : (ce - 1);
            aP[i] = A + (size_t)(eb + drow) * K + asub[i] * 8;
        }
#pragma unroll
        for (int i = 0; i < 8; i++)
            bP[i] = Bw + ((size_t)e * N + n0 + brow[i]) * K + bsub[i] * 8;

        f32x4 acc[2][8];
#pragma unroll
        for (int mi = 0; mi < 2; mi++)
#pragma unroll
            for (int ni = 0; ni < 8; ni++) acc[mi][ni] = (f32x4){0, 0, 0, 0};

        for (int k0 = 0; k0 < K; k0 += 64) {
#pragma unroll
            for (int i = 0; i < 2; i++)
                gload16(aP[i] + k0, Asm + (wid * 2 + i) * 512);
#pragma unroll
            for (int i = 0; i < 8; i++)
                gload16(bP[i] + k0, Bsm + (wid * 8 + i) * 512);
            __syncthreads();
#pragma unroll
            for (int kf = 0; kf < 2; kf++) {
                const int phys = ((kf * 4 + lq) ^ (lr & 7)) * 8;
                bf16x8 af[2], bfr[8];
#pragma unroll
                for (int mi = 0; mi < 2; mi++)
                    af[mi] = as_bf(*(const u16x8*)&Asm[(moff + mi * 16 + lr) * 64 + phys]);
#pragma unroll
                for (int ni = 0; ni < 8; ni++)
                    bfr[ni] = as_bf(*(const u16x8*)&Bsm[(noff + ni * 16 + lr) * 64 + phys]);
#pragma unroll
                for (int mi = 0; mi < 2; mi++)
#pragma unroll
                    for (int ni = 0; ni < 8; ni++)
                        acc[mi][ni] = __builtin_amdgcn_mfma_f32_16x16x32_bf16(
                            af[mi], bfr[ni], acc[mi][ni], 0, 0, 0);
            }
            __syncthreads();
        }

#pragma unroll
        for (int mi = 0; mi < 2; mi++) {
#pragma unroll
            for (int r4 = 0; r4 < 4; r4++) {
                const int row = moff + mi * 16 + lq * 4 + r4;
                if (m0 + row < ce) {
                    const int tok = tokrow[row];
                    const float tp = topp[tok];
#pragma unroll
                    for (int ni = 0; ni < 8; ni++) {
                        const size_t idx = (size_t)tok * DIM + n0 + noff + ni * 16 + lr;
                        out[idx] = hs[idx] + tp * acc[mi][ni][r4];
                    }
                }
            }
        }
    }
}

// ---------------------------------------------------------------------------
extern "C" void kernel_launch(void* const* d_in, const int* in_sizes, int n_in,
                              void* d_out, int out_size, void* d_ws, size_t ws_size,
                              hipStream_t stream)
{
    const float* hs  = (const float*)d_in[0];
    const float* lnw = (const float*)d_in[1];
    const float* rw  = (const float*)d_in[2];
    const float* wi  = (const float*)d_in[3];
    const float* wo  = (const float*)d_in[4];

    float* out        = (float*)d_out;
    float* out_logits = out + (size_t)N_TOK * DIM;
    float* out_eidx   = out_logits + (size_t)N_TOK * NEXP;

    char* ws = (char*)d_ws;
    size_t off = 0;
    int*   cnt     = (int*)(ws + off);         off += 256;
    int*   list    = (int*)(ws + off);         off += (size_t)N_TOK * 4;
    float* topp    = (float*)(ws + off);       off += (size_t)N_TOK * 4;
    int*   eidx    = (int*)(ws + off);         off += (size_t)N_TOK * 4;
    int*   blkhist = (int*)(ws + off);         off += 4096;
    int*   base    = (int*)(ws + off);         off += 4096;
    unsigned short* xn  = (unsigned short*)(ws + off); off += (size_t)N_TOK * DIM * 2;
    unsigned short* Hb  = (unsigned short*)(ws + off); off += (size_t)N_TOK * FFD * 2;
    unsigned short* wob = (unsigned short*)(ws + off);

    // wi^T (bf16 [e][F][D]) lives in d_out's first 37.75 MB: dead before
    // GEMM2's epilogue writes `out`.
    unsigned short* wib = (unsigned short*)d_out;

    k_convT<<<NEXP * (DIM / 64) * (FFD / 64), 256, 0, stream>>>(wi, wib, DIM, FFD);
    k_convT<<<NEXP * (FFD / 64) * (DIM / 64), 256, 0, stream>>>(wo, wob, FFD, DIM);
    k_router<<<N_TOK / 4, 256, 0, stream>>>(hs, lnw, rw, out_logits, out_eidx,
                                            topp, eidx, xn);
    k_hist<<<64, 256, 0, stream>>>(eidx, blkhist);
    k_prefix<<<1, 512, 0, stream>>>(blkhist, base, cnt);
    k_scatter<<<64, 256, 0, stream>>>(eidx, base, list);
    k_gemm1<<<1632, 256, 0, stream>>>(xn, wib, list, cnt, Hb);
    k_gemm2<<<768, 256, 0, stream>>>(Hb, wob, list, cnt, hs, topp, out);
}

// Round 7
// 329.513 us; speedup vs baseline: 1.0437x; 1.0437x over previous
//
#include <hip/hip_runtime.h>
#include <math.h>

#define N_TOK 16384
#define DIM   768
#define FFD   3072
#define NEXP  8
#define EPSV  1e-6f

typedef __attribute__((ext_vector_type(4))) float f32x4;
typedef __attribute__((ext_vector_type(4))) unsigned short u16x4;
typedef __attribute__((ext_vector_type(8))) unsigned short u16x8;
typedef __attribute__((ext_vector_type(8))) __bf16 bf16x8;

static __device__ __forceinline__ unsigned short f2bf(float f) {
    unsigned int u = __builtin_bit_cast(unsigned int, f);
    u += 0x7fffu + ((u >> 16) & 1u);   // round-to-nearest-even
    return (unsigned short)(u >> 16);
}
static __device__ __forceinline__ bf16x8 as_bf(u16x8 v) {
    return __builtin_bit_cast(bf16x8, v);
}
static __device__ __forceinline__ void gload16(const void* g, void* l) {
    __builtin_amdgcn_global_load_lds(
        (const __attribute__((address_space(1))) unsigned int*)g,
        (__attribute__((address_space(3))) unsigned int*)l, 16, 0, 0);
}

// ---------------------------------------------------------------------------
// Kernel 0: convert+transpose  in[e][R][C] f32  ->  out[e][C][R] bf16
// ---------------------------------------------------------------------------
__global__ __launch_bounds__(256) void k_convT(
    const float* __restrict__ in, unsigned short* __restrict__ outp,
    int R, int C)
{
    __shared__ float tile[64][68];
    const int bc = C >> 6, br = R >> 6;
    const int b = blockIdx.x;
    const int e = b / (bc * br);
    const int rem = b - e * bc * br;
    const int rt = rem / bc, ct = rem - rt * bc;
    const int t = threadIdx.x;
    {
        const int r = t >> 2, c4 = (t & 3) << 4;
        const float* src = in + ((size_t)e * R + rt * 64 + r) * C + ct * 64 + c4;
#pragma unroll
        for (int q = 0; q < 4; q++) {
            float4 f = ((const float4*)src)[q];
            tile[r][c4 + q * 4 + 0] = f.x;
            tile[r][c4 + q * 4 + 1] = f.y;
            tile[r][c4 + q * 4 + 2] = f.z;
            tile[r][c4 + q * 4 + 3] = f.w;
        }
    }
    __syncthreads();
    {
        const int c = t >> 2, r4 = (t & 3) << 4;
        u16x8 o0, o1;
#pragma unroll
        for (int j = 0; j < 8; j++)  o0[j] = f2bf(tile[r4 + j][c]);
#pragma unroll
        for (int j = 0; j < 8; j++)  o1[j] = f2bf(tile[r4 + 8 + j][c]);
        unsigned short* dst = outp + ((size_t)e * C + ct * 64 + c) * R + rt * 64 + r4;
        *(u16x8*)dst       = o0;
        *(u16x8*)(dst + 8) = o1;
    }
}

// ---------------------------------------------------------------------------
// Kernel 1: RMSNorm + router, one wave per token. NO global atomics.
// ---------------------------------------------------------------------------
__global__ __launch_bounds__(256) void k_router(
    const float* __restrict__ x, const float* __restrict__ lnw,
    const float* __restrict__ rw,
    float* __restrict__ out_logits, float* __restrict__ out_eidx,
    float* __restrict__ topp, int* __restrict__ eidx,
    unsigned short* __restrict__ xn)
{
    const int wid = threadIdx.x >> 6, lane = threadIdx.x & 63;
    const int tok = blockIdx.x * 4 + wid;
    const size_t base = (size_t)tok * DIM;

    float4 v[3];
#pragma unroll
    for (int j = 0; j < 3; j++)
        v[j] = *(const float4*)(x + base + lane * 4 + j * 256);
    float ss = 0.f;
#pragma unroll
    for (int j = 0; j < 3; j++)
        ss += v[j].x * v[j].x + v[j].y * v[j].y + v[j].z * v[j].z + v[j].w * v[j].w;
#pragma unroll
    for (int s = 32; s > 0; s >>= 1) ss += __shfl_xor(ss, s);
    const float rstd = rsqrtf(ss * (1.0f / DIM) + EPSV);

    float rp[8];
#pragma unroll
    for (int e = 0; e < 8; e++) rp[e] = 0.f;
#pragma unroll
    for (int j = 0; j < 3; j++) {
        float4 lw = *(const float4*)(lnw + lane * 4 + j * 256);
        float xv[4] = { v[j].x * rstd * lw.x, v[j].y * rstd * lw.y,
                        v[j].z * rstd * lw.z, v[j].w * rstd * lw.w };
        u16x4 pk = { f2bf(xv[0]), f2bf(xv[1]), f2bf(xv[2]), f2bf(xv[3]) };
        *(u16x4*)(xn + base + lane * 4 + j * 256) = pk;
#pragma unroll
        for (int i = 0; i < 4; i++) {
            const int d = lane * 4 + j * 256 + i;
            const float4* rr = (const float4*)(rw + (size_t)d * 8);
            float4 a = rr[0], bq = rr[1];
            rp[0] += xv[i] * a.x;  rp[1] += xv[i] * a.y;
            rp[2] += xv[i] * a.z;  rp[3] += xv[i] * a.w;
            rp[4] += xv[i] * bq.x; rp[5] += xv[i] * bq.y;
            rp[6] += xv[i] * bq.z; rp[7] += xv[i] * bq.w;
        }
    }
#pragma unroll
    for (int s = 32; s > 0; s >>= 1) {
#pragma unroll
        for (int e = 0; e < 8; e++) rp[e] += __shfl_xor(rp[e], s);
    }
    if (lane == 0) {
        float m = -1e30f; int am = 0;
#pragma unroll
        for (int e = 0; e < 8; e++) {
            out_logits[(size_t)tok * 8 + e] = rp[e];
            if (rp[e] > m) { m = rp[e]; am = e; }
        }
        float se = 0.f;
#pragma unroll
        for (int e = 0; e < 8; e++) se += expf(rp[e] - m);
        topp[tok] = 1.0f / se;
        out_eidx[tok] = (float)am;
        eidx[tok] = am;
    }
}

// ---------------------------------------------------------------------------
// Kernel 2a: per-block expert histogram (64 blocks x 256 tokens).
// ---------------------------------------------------------------------------
__global__ __launch_bounds__(256) void k_hist(
    const int* __restrict__ eidx, int* __restrict__ blkhist)
{
    __shared__ int h[8];
    if (threadIdx.x < 8) h[threadIdx.x] = 0;
    __syncthreads();
    atomicAdd(&h[eidx[blockIdx.x * 256 + threadIdx.x]], 1);
    __syncthreads();
    if (threadIdx.x < 8) blkhist[blockIdx.x * 8 + threadIdx.x] = h[threadIdx.x];
}

// ---------------------------------------------------------------------------
// Kernel 2b: one-block prefix over the 64x8 histogram.
// ---------------------------------------------------------------------------
__global__ __launch_bounds__(512) void k_prefix(
    const int* __restrict__ blkhist, int* __restrict__ base,
    int* __restrict__ cnt)
{
    __shared__ int h[64 * 8];
    __shared__ int tot[8];
    __shared__ int eb[8];
    const int t = threadIdx.x;
    h[t] = blkhist[t];
    __syncthreads();
    const int b = t >> 3, e = t & 7;
    int s = 0;
    for (int bb = 0; bb < b; bb++) s += h[bb * 8 + e];
    if (b == 63) tot[e] = s + h[63 * 8 + e];
    __syncthreads();
    if (t == 0) {
        int p = 0;
#pragma unroll
        for (int q = 0; q < 8; q++) { eb[q] = p; p += tot[q]; }
    }
    __syncthreads();
    base[t] = eb[e] + s;
    if (t < 8) cnt[t] = tot[t];
}

// ---------------------------------------------------------------------------
// Kernel 2c: deterministic stable scatter using precomputed bases.
// ---------------------------------------------------------------------------
__global__ __launch_bounds__(256) void k_scatter(
    const int* __restrict__ eidx, const int* __restrict__ base,
    int* __restrict__ list)
{
    __shared__ int wcnt[4][8];
    __shared__ int bb[8];
    const int t = threadIdx.x, b = blockIdx.x;
    const int lane = t & 63, wid = t >> 6;
    if (t < 8) bb[t] = base[b * 8 + t];
    const int tok = b * 256 + t;
    const int e = eidx[tok];
    int wrank = 0;
#pragma unroll
    for (int q = 0; q < 8; q++) {
        unsigned long long m = __ballot(e == q);
        if (e == q) wrank = __popcll(m & ((1ull << lane) - 1ull));
        if (lane == 0) wcnt[wid][q] = __popcll(m);
    }
    __syncthreads();
    int wbase = 0;
#pragma unroll
    for (int w = 0; w < 4; w++)
        if (w < wid) wbase += wcnt[w][e];
    list[bb[e] + wbase + wrank] = tok;
}

// ---------------------------------------------------------------------------
// GEMM1: 128x256 tile, BK=32, TRUE overlapped 2-phase: double-buffered LDS,
// stage(t+1 -> buf^1) issued BEFORE the MFMAs on buf[cur], ONE __syncthreads
// per K-step AFTER the MFMAs (its vmcnt0 drain covers only next-tile loads,
// which have been hiding under the compute). LDS 48KB -> up to 3 blocks/CU.
// Hperm[denserow,:] = relu(Xn[tok,:] @ WiT)   (A gathered via token list)
// ---------------------------------------------------------------------------
__global__ __launch_bounds__(256, 2) void k_gemm1(
    const unsigned short* __restrict__ A, const unsigned short* __restrict__ Bw,
    const int* __restrict__ list, const int* __restrict__ cnt,
    unsigned short* __restrict__ Hout)
{
    constexpr int K   = DIM;                      // 768
    constexpr int N   = FFD;                      // 3072
    constexpr int TNT = N / 256;                  // 12
    constexpr int NT  = K / 32;                   // 24
    __shared__ unsigned short Asm[2][128 * 32];   // 16 KB
    __shared__ unsigned short Bsm[2][256 * 32];   // 32 KB
    __shared__ int tokrow[128];
    __shared__ int spref[9];
    __shared__ int ebase[8];

    const int t = threadIdx.x, lane = t & 63, wid = t >> 6;
    if (t == 0) {
        int p = 0, qq = 0;
        spref[0] = 0;
#pragma unroll
        for (int e = 0; e < 8; e++) {
            ebase[e] = qq; qq += cnt[e];
            p += (cnt[e] + 127) >> 7;
            spref[e + 1] = p;
        }
    }
    __syncthreads();
    const int total = spref[8] * TNT;
    const int moff = (wid >> 1) * 64, noff = (wid & 1) * 128;
    const int lr = lane & 15, lq = lane >> 4;
    const int physo = (lq ^ ((lr >> 1) & 3)) * 8;   // read-side swizzle (32-el rows)

    const int nwg = gridDim.x;
    const int xcd = blockIdx.x & 7, rr8 = blockIdx.x >> 3;
    const int qd = nwg >> 3, rm = nwg & 7;
    const int bid = (xcd < rm ? xcd * (qd + 1) : rm * (qd + 1) + (xcd - rm) * qd) + rr8;

    // staging chunk geometry: rows of 32 elems = 4 chunks of 16B.
    // LDS slot (c&3) of row (c>>2) holds global sub (c&3)^((row>>1)&3).
    int arow[2], asub[2], brow[4], bsub[4];
#pragma unroll
    for (int i = 0; i < 2; i++) {
        int c = (wid * 2 + i) * 64 + lane;        // 0..511 (128 rows x 4)
        arow[i] = c >> 2;
        asub[i] = (c & 3) ^ ((arow[i] >> 1) & 3);
    }
#pragma unroll
    for (int i = 0; i < 4; i++) {
        int c = (wid * 4 + i) * 64 + lane;        // 0..1023 (256 rows x 4)
        brow[i] = c >> 2;
        bsub[i] = (c & 3) ^ ((brow[i] >> 1) & 3);
    }

    for (int w = bid; w < total; w += gridDim.x) {
        const int gm = w / TNT, tn = w - gm * TNT;
        int e = 0;
        while (gm >= spref[e + 1]) e++;
        const int ce = cnt[e], eb = ebase[e];
        const int m0 = (gm - spref[e]) * 128, n0 = tn * 256;

        __syncthreads();
        if (t < 128)
            tokrow[t] = (m0 + t < ce) ? list[eb + m0 + t] : list[eb];
        __syncthreads();

        const unsigned short* aP[2];
        const unsigned short* bP[4];
#pragma unroll
        for (int i = 0; i < 2; i++)
            aP[i] = A + (size_t)tokrow[arow[i]] * K + asub[i] * 8;
#pragma unroll
        for (int i = 0; i < 4; i++)
            bP[i] = Bw + ((size_t)e * N + n0 + brow[i]) * K + bsub[i] * 8;

        f32x4 acc[4][8];
#pragma unroll
        for (int mi = 0; mi < 4; mi++)
#pragma unroll
            for (int ni = 0; ni < 8; ni++) acc[mi][ni] = (f32x4){0, 0, 0, 0};

        // prologue: stage k-step 0 into buffer 0, drain, sync
#pragma unroll
        for (int i = 0; i < 2; i++)
            gload16(aP[i], &Asm[0][(wid * 2 + i) * 512]);
#pragma unroll
        for (int i = 0; i < 4; i++)
            gload16(bP[i], &Bsm[0][(wid * 4 + i) * 512]);
        __syncthreads();

        int cur = 0;
        for (int tk = 0; tk < NT; ++tk) {
            if (tk + 1 < NT) {
                const int k0n = (tk + 1) * 32;
#pragma unroll
                for (int i = 0; i < 2; i++)
                    gload16(aP[i] + k0n, &Asm[cur ^ 1][(wid * 2 + i) * 512]);
#pragma unroll
                for (int i = 0; i < 4; i++)
                    gload16(bP[i] + k0n, &Bsm[cur ^ 1][(wid * 4 + i) * 512]);
            }
            bf16x8 af[4], bfr[8];
#pragma unroll
            for (int mi = 0; mi < 4; mi++)
                af[mi] = as_bf(*(const u16x8*)&Asm[cur][(moff + mi * 16 + lr) * 32 + physo]);
#pragma unroll
            for (int ni = 0; ni < 8; ni++)
                bfr[ni] = as_bf(*(const u16x8*)&Bsm[cur][(noff + ni * 16 + lr) * 32 + physo]);
#pragma unroll
            for (int mi = 0; mi < 4; mi++)
#pragma unroll
                for (int ni = 0; ni < 8; ni++)
                    acc[mi][ni] = __builtin_amdgcn_mfma_f32_16x16x32_bf16(
                        af[mi], bfr[ni], acc[mi][ni], 0, 0, 0);
            __syncthreads();   // vmcnt0 drain (next-tile loads) + all waves done reading cur
            cur ^= 1;
        }

#pragma unroll
        for (int mi = 0; mi < 4; mi++) {
#pragma unroll
            for (int r4 = 0; r4 < 4; r4++) {
                const int row = moff + mi * 16 + lq * 4 + r4;
                if (m0 + row < ce) {
                    unsigned short* hp = Hout + (size_t)(eb + m0 + row) * FFD + n0 + noff;
#pragma unroll
                    for (int ni = 0; ni < 8; ni++) {
                        float v = acc[mi][ni][r4];
                        v = v > 0.f ? v : 0.f;
                        hp[ni * 16 + lr] = f2bf(v);
                    }
                }
            }
        }
    }
}

// ---------------------------------------------------------------------------
// GEMM2: 128x256 tile, BK=64, single-buffer 2-barrier (proven ~119us), dense
// A rows from permuted H.
// out[tok,:] = hs[tok,:] + topp[tok]*(Hperm[denserow,:] @ WoT)
// ---------------------------------------------------------------------------
__global__ __launch_bounds__(256, 2) void k_gemm2(
    const unsigned short* __restrict__ A, const unsigned short* __restrict__ Bw,
    const int* __restrict__ list, const int* __restrict__ cnt,
    const float* __restrict__ hs, const float* __restrict__ topp,
    float* __restrict__ out)
{
    constexpr int K   = FFD;
    constexpr int N   = DIM;
    constexpr int TNT = N / 256;                  // 3
    __shared__ unsigned short Asm[128 * 64];      // 16 KB
    __shared__ unsigned short Bsm[256 * 64];      // 32 KB
    __shared__ int tokrow[128];
    __shared__ int spref[9];
    __shared__ int ebase[8];

    const int t = threadIdx.x, lane = t & 63, wid = t >> 6;
    if (t == 0) {
        int p = 0, qq = 0;
        spref[0] = 0;
#pragma unroll
        for (int e = 0; e < 8; e++) {
            ebase[e] = qq; qq += cnt[e];
            p += (cnt[e] + 127) >> 7;
            spref[e + 1] = p;
        }
    }
    __syncthreads();
    const int total = spref[8] * TNT;
    const int moff = (wid >> 1) * 64, noff = (wid & 1) * 128;
    const int lr = lane & 15, lq = lane >> 4;

    const int nwg = gridDim.x;
    const int xcd = blockIdx.x & 7, rr8 = blockIdx.x >> 3;
    const int qd = nwg >> 3, rm = nwg & 7;
    const int bid = (xcd < rm ? xcd * (qd + 1) : rm * (qd + 1) + (xcd - rm) * qd) + rr8;

    int arow[4], asub[4], brow[8], bsub[8];
#pragma unroll
    for (int i = 0; i < 4; i++) {
        int c = (wid * 4 + i) * 64 + lane;
        arow[i] = c >> 3;
        asub[i] = (c & 7) ^ (arow[i] & 7);
    }
#pragma unroll
    for (int i = 0; i < 8; i++) {
        int c = (wid * 8 + i) * 64 + lane;
        brow[i] = c >> 3;
        bsub[i] = (c & 7) ^ (brow[i] & 7);
    }

    for (int w = bid; w < total; w += gridDim.x) {
        const int gm = w / TNT, tn = w - gm * TNT;
        int e = 0;
        while (gm >= spref[e + 1]) e++;
        const int ce = cnt[e], eb = ebase[e];
        const int m0 = (gm - spref[e]) * 128, n0 = tn * 256;

        __syncthreads();
        if (t < 128)
            tokrow[t] = (m0 + t < ce) ? list[eb + m0 + t] : list[eb];
        __syncthreads();

        const unsigned short* aP[4];
        const unsigned short* bP[8];
#pragma unroll
        for (int i = 0; i < 4; i++) {
            const int drow = (m0 + arow[i] < ce) ? (m0 + arow[i]) : (ce - 1);
            aP[i] = A + (size_t)(eb + drow) * K + asub[i] * 8;
        }
#pragma unroll
        for (int i = 0; i < 8; i++)
            bP[i] = Bw + ((size_t)e * N + n0 + brow[i]) * K + bsub[i] * 8;

        f32x4 acc[4][8];
#pragma unroll
        for (int mi = 0; mi < 4; mi++)
#pragma unroll
            for (int ni = 0; ni < 8; ni++) acc[mi][ni] = (f32x4){0, 0, 0, 0};

        for (int k0 = 0; k0 < K; k0 += 64) {
#pragma unroll
            for (int i = 0; i < 4; i++)
                gload16(aP[i] + k0, Asm + (wid * 4 + i) * 512);
#pragma unroll
            for (int i = 0; i < 8; i++)
                gload16(bP[i] + k0, Bsm + (wid * 8 + i) * 512);
            __syncthreads();
#pragma unroll
            for (int kf = 0; kf < 2; kf++) {
                const int phys = ((kf * 4 + lq) ^ (lr & 7)) * 8;
                bf16x8 af[4], bfr[8];
#pragma unroll
                for (int mi = 0; mi < 4; mi++)
                    af[mi] = as_bf(*(const u16x8*)&Asm[(moff + mi * 16 + lr) * 64 + phys]);
#pragma unroll
                for (int ni = 0; ni < 8; ni++)
                    bfr[ni] = as_bf(*(const u16x8*)&Bsm[(noff + ni * 16 + lr) * 64 + phys]);
#pragma unroll
                for (int mi = 0; mi < 4; mi++)
#pragma unroll
                    for (int ni = 0; ni < 8; ni++)
                        acc[mi][ni] = __builtin_amdgcn_mfma_f32_16x16x32_bf16(
                            af[mi], bfr[ni], acc[mi][ni], 0, 0, 0);
            }
            __syncthreads();
        }

#pragma unroll
        for (int mi = 0; mi < 4; mi++) {
#pragma unroll
            for (int r4 = 0; r4 < 4; r4++) {
                const int row = moff + mi * 16 + lq * 4 + r4;
                if (m0 + row < ce) {
                    const int tok = tokrow[row];
                    const float tp = topp[tok];
#pragma unroll
                    for (int ni = 0; ni < 8; ni++) {
                        const size_t idx = (size_t)tok * DIM + n0 + noff + ni * 16 + lr;
                        out[idx] = hs[idx] + tp * acc[mi][ni][r4];
                    }
                }
            }
        }
    }
}

// ---------------------------------------------------------------------------
extern "C" void kernel_launch(void* const* d_in, const int* in_sizes, int n_in,
                              void* d_out, int out_size, void* d_ws, size_t ws_size,
                              hipStream_t stream)
{
    const float* hs  = (const float*)d_in[0];
    const float* lnw = (const float*)d_in[1];
    const float* rw  = (const float*)d_in[2];
    const float* wi  = (const float*)d_in[3];
    const float* wo  = (const float*)d_in[4];

    float* out        = (float*)d_out;
    float* out_logits = out + (size_t)N_TOK * DIM;
    float* out_eidx   = out_logits + (size_t)N_TOK * NEXP;

    char* ws = (char*)d_ws;
    size_t off = 0;
    int*   cnt     = (int*)(ws + off);         off += 256;
    int*   list    = (int*)(ws + off);         off += (size_t)N_TOK * 4;
    float* topp    = (float*)(ws + off);       off += (size_t)N_TOK * 4;
    int*   eidx    = (int*)(ws + off);         off += (size_t)N_TOK * 4;
    int*   blkhist = (int*)(ws + off);         off += 4096;
    int*   base    = (int*)(ws + off);         off += 4096;
    unsigned short* xn  = (unsigned short*)(ws + off); off += (size_t)N_TOK * DIM * 2;
    unsigned short* Hb  = (unsigned short*)(ws + off); off += (size_t)N_TOK * FFD * 2;
    unsigned short* wob = (unsigned short*)(ws + off);

    // wi^T (bf16 [e][F][D]) lives in d_out's first 37.75 MB: dead before
    // GEMM2's epilogue writes `out`.
    unsigned short* wib = (unsigned short*)d_out;

    k_convT<<<NEXP * (DIM / 64) * (FFD / 64), 256, 0, stream>>>(wi, wib, DIM, FFD);
    k_convT<<<NEXP * (FFD / 64) * (DIM / 64), 256, 0, stream>>>(wo, wob, FFD, DIM);
    k_router<<<N_TOK / 4, 256, 0, stream>>>(hs, lnw, rw, out_logits, out_eidx,
                                            topp, eidx, xn);
    k_hist<<<64, 256, 0, stream>>>(eidx, blkhist);
    k_prefix<<<1, 512, 0, stream>>>(blkhist, base, cnt);
    k_scatter<<<64, 256, 0, stream>>>(eidx, base, list);
    k_gemm1<<<1632, 256, 0, stream>>>(xn, wib, list, cnt, Hb);
    k_gemm2<<<408, 256, 0, stream>>>(Hb, wob, list, cnt, hs, topp, out);
}

// Round 8
// 299.196 us; speedup vs baseline: 1.1494x; 1.1013x over previous
//
#include <hip/hip_runtime.h>
#include <math.h>

#define N_TOK 16384
#define DIM   768
#define FFD   3072
#define NEXP  8
#define EPSV  1e-6f

typedef __attribute__((ext_vector_type(4))) float f32x4;
typedef __attribute__((ext_vector_type(4))) unsigned short u16x4;
typedef __attribute__((ext_vector_type(8))) unsigned short u16x8;
typedef __attribute__((ext_vector_type(8))) __bf16 bf16x8;

static __device__ __forceinline__ unsigned short f2bf(float f) {
    unsigned int u = __builtin_bit_cast(unsigned int, f);
    u += 0x7fffu + ((u >> 16) & 1u);   // round-to-nearest-even
    return (unsigned short)(u >> 16);
}
static __device__ __forceinline__ bf16x8 as_bf(u16x8 v) {
    return __builtin_bit_cast(bf16x8, v);
}
static __device__ __forceinline__ void gload16(const void* g, void* l) {
    __builtin_amdgcn_global_load_lds(
        (const __attribute__((address_space(1))) unsigned int*)g,
        (__attribute__((address_space(3))) unsigned int*)l, 16, 0, 0);
}

// ---------------------------------------------------------------------------
// Fused setup kernel: blocks [0,4608) convert wi, [4608,9216) convert wo,
// [9216,13312) run RMSNorm+router. All three are independent + BW-bound;
// fusing overlaps their HBM traffic instead of serializing three launches.
// ---------------------------------------------------------------------------
__global__ __launch_bounds__(256) void k_setup(
    const float* __restrict__ wi, unsigned short* __restrict__ wib,
    const float* __restrict__ wo, unsigned short* __restrict__ wob,
    const float* __restrict__ x, const float* __restrict__ lnw,
    const float* __restrict__ rw,
    float* __restrict__ out_logits, float* __restrict__ out_eidx,
    float* __restrict__ topp, int* __restrict__ eidx,
    unsigned short* __restrict__ xn)
{
    __shared__ float tile[64][68];
    const int t = threadIdx.x;
    const int b = blockIdx.x;

    if (b < 9216) {
        // ---- convert+transpose  in[e][R][C] f32 -> out[e][C][R] bf16 ----
        const float* in;
        unsigned short* outp;
        int R, C, bb;
        if (b < 4608) { in = wi; outp = wib; R = DIM; C = FFD; bb = b; }
        else          { in = wo; outp = wob; R = FFD; C = DIM; bb = b - 4608; }
        const int bc = C >> 6, br = R >> 6;
        const int e = bb / (bc * br);
        const int rem = bb - e * bc * br;
        const int rt = rem / bc, ct = rem - rt * bc;
        {
            const int r = t >> 2, c4 = (t & 3) << 4;
            const float* src = in + ((size_t)e * R + rt * 64 + r) * C + ct * 64 + c4;
#pragma unroll
            for (int q = 0; q < 4; q++) {
                float4 f = ((const float4*)src)[q];
                tile[r][c4 + q * 4 + 0] = f.x;
                tile[r][c4 + q * 4 + 1] = f.y;
                tile[r][c4 + q * 4 + 2] = f.z;
                tile[r][c4 + q * 4 + 3] = f.w;
            }
        }
        __syncthreads();
        {
            const int c = t >> 2, r4 = (t & 3) << 4;
            u16x8 o0, o1;
#pragma unroll
            for (int j = 0; j < 8; j++)  o0[j] = f2bf(tile[r4 + j][c]);
#pragma unroll
            for (int j = 0; j < 8; j++)  o1[j] = f2bf(tile[r4 + 8 + j][c]);
            unsigned short* dst = outp + ((size_t)e * C + ct * 64 + c) * R + rt * 64 + r4;
            *(u16x8*)dst       = o0;
            *(u16x8*)(dst + 8) = o1;
        }
        return;
    }

    // ---- RMSNorm + router: one wave per token ----
    const int wid = t >> 6, lane = t & 63;
    const int tok = (b - 9216) * 4 + wid;
    const size_t base = (size_t)tok * DIM;

    float4 v[3];
#pragma unroll
    for (int j = 0; j < 3; j++)
        v[j] = *(const float4*)(x + base + lane * 4 + j * 256);
    float ss = 0.f;
#pragma unroll
    for (int j = 0; j < 3; j++)
        ss += v[j].x * v[j].x + v[j].y * v[j].y + v[j].z * v[j].z + v[j].w * v[j].w;
#pragma unroll
    for (int s = 32; s > 0; s >>= 1) ss += __shfl_xor(ss, s);
    const float rstd = rsqrtf(ss * (1.0f / DIM) + EPSV);

    float rp[8];
#pragma unroll
    for (int e = 0; e < 8; e++) rp[e] = 0.f;
#pragma unroll
    for (int j = 0; j < 3; j++) {
        float4 lw = *(const float4*)(lnw + lane * 4 + j * 256);
        float xv[4] = { v[j].x * rstd * lw.x, v[j].y * rstd * lw.y,
                        v[j].z * rstd * lw.z, v[j].w * rstd * lw.w };
        u16x4 pk = { f2bf(xv[0]), f2bf(xv[1]), f2bf(xv[2]), f2bf(xv[3]) };
        *(u16x4*)(xn + base + lane * 4 + j * 256) = pk;
#pragma unroll
        for (int i = 0; i < 4; i++) {
            const int d = lane * 4 + j * 256 + i;
            const float4* rr = (const float4*)(rw + (size_t)d * 8);
            float4 a = rr[0], bq = rr[1];
            rp[0] += xv[i] * a.x;  rp[1] += xv[i] * a.y;
            rp[2] += xv[i] * a.z;  rp[3] += xv[i] * a.w;
            rp[4] += xv[i] * bq.x; rp[5] += xv[i] * bq.y;
            rp[6] += xv[i] * bq.z; rp[7] += xv[i] * bq.w;
        }
    }
#pragma unroll
    for (int s = 32; s > 0; s >>= 1) {
#pragma unroll
        for (int e = 0; e < 8; e++) rp[e] += __shfl_xor(rp[e], s);
    }
    if (lane == 0) {
        float m = -1e30f; int am = 0;
#pragma unroll
        for (int e = 0; e < 8; e++) {
            out_logits[(size_t)tok * 8 + e] = rp[e];
            if (rp[e] > m) { m = rp[e]; am = e; }
        }
        float se = 0.f;
#pragma unroll
        for (int e = 0; e < 8; e++) se += expf(rp[e] - m);
        topp[tok] = 1.0f / se;
        out_eidx[tok] = (float)am;
        eidx[tok] = am;
    }
}

// ---------------------------------------------------------------------------
// Kernel 2a: per-block expert histogram (64 blocks x 256 tokens).
// ---------------------------------------------------------------------------
__global__ __launch_bounds__(256) void k_hist(
    const int* __restrict__ eidx, int* __restrict__ blkhist)
{
    __shared__ int h[8];
    if (threadIdx.x < 8) h[threadIdx.x] = 0;
    __syncthreads();
    atomicAdd(&h[eidx[blockIdx.x * 256 + threadIdx.x]], 1);
    __syncthreads();
    if (threadIdx.x < 8) blkhist[blockIdx.x * 8 + threadIdx.x] = h[threadIdx.x];
}

// ---------------------------------------------------------------------------
// Kernel 2b: one-block prefix over the 64x8 histogram.
// ---------------------------------------------------------------------------
__global__ __launch_bounds__(512) void k_prefix(
    const int* __restrict__ blkhist, int* __restrict__ base,
    int* __restrict__ cnt)
{
    __shared__ int h[64 * 8];
    __shared__ int tot[8];
    __shared__ int eb[8];
    const int t = threadIdx.x;
    h[t] = blkhist[t];
    __syncthreads();
    const int b = t >> 3, e = t & 7;
    int s = 0;
    for (int bb = 0; bb < b; bb++) s += h[bb * 8 + e];
    if (b == 63) tot[e] = s + h[63 * 8 + e];
    __syncthreads();
    if (t == 0) {
        int p = 0;
#pragma unroll
        for (int q = 0; q < 8; q++) { eb[q] = p; p += tot[q]; }
    }
    __syncthreads();
    base[t] = eb[e] + s;
    if (t < 8) cnt[t] = tot[t];
}

// ---------------------------------------------------------------------------
// Kernel 2c: deterministic stable scatter using precomputed bases.
// ---------------------------------------------------------------------------
__global__ __launch_bounds__(256) void k_scatter(
    const int* __restrict__ eidx, const int* __restrict__ base,
    int* __restrict__ list)
{
    __shared__ int wcnt[4][8];
    __shared__ int bb[8];
    const int t = threadIdx.x, b = blockIdx.x;
    const int lane = t & 63, wid = t >> 6;
    if (t < 8) bb[t] = base[b * 8 + t];
    const int tok = b * 256 + t;
    const int e = eidx[tok];
    int wrank = 0;
#pragma unroll
    for (int q = 0; q < 8; q++) {
        unsigned long long m = __ballot(e == q);
        if (e == q) wrank = __popcll(m & ((1ull << lane) - 1ull));
        if (lane == 0) wcnt[wid][q] = __popcll(m);
    }
    __syncthreads();
    int wbase = 0;
#pragma unroll
    for (int w = 0; w < 4; w++)
        if (w < wid) wbase += wcnt[w][e];
    list[bb[e] + wbase + wrank] = tok;
}

// ---------------------------------------------------------------------------
// GEMM1: 128x256 tile, BK=64, single-buffer 2-barrier (proven ~115us),
// A gathered via token list, H written in dense (permuted) row order.
// ---------------------------------------------------------------------------
__global__ __launch_bounds__(256, 2) void k_gemm1(
    const unsigned short* __restrict__ A, const unsigned short* __restrict__ Bw,
    const int* __restrict__ list, const int* __restrict__ cnt,
    unsigned short* __restrict__ Hout)
{
    constexpr int K   = DIM;
    constexpr int N   = FFD;
    constexpr int TNT = N / 256;                  // 12
    __shared__ unsigned short Asm[128 * 64];      // 16 KB
    __shared__ unsigned short Bsm[256 * 64];      // 32 KB
    __shared__ int tokrow[128];
    __shared__ int spref[9];
    __shared__ int ebase[8];

    const int t = threadIdx.x, lane = t & 63, wid = t >> 6;
    if (t == 0) {
        int p = 0, qq = 0;
        spref[0] = 0;
#pragma unroll
        for (int e = 0; e < 8; e++) {
            ebase[e] = qq; qq += cnt[e];
            p += (cnt[e] + 127) >> 7;
            spref[e + 1] = p;
        }
    }
    __syncthreads();
    const int total = spref[8] * TNT;
    const int moff = (wid >> 1) * 64, noff = (wid & 1) * 128;
    const int lr = lane & 15, lq = lane >> 4;

    const int nwg = gridDim.x;
    const int xcd = blockIdx.x & 7, rr8 = blockIdx.x >> 3;
    const int qd = nwg >> 3, rm = nwg & 7;
    const int bid = (xcd < rm ? xcd * (qd + 1) : rm * (qd + 1) + (xcd - rm) * qd) + rr8;

    int arow[4], asub[4], brow[8], bsub[8];
#pragma unroll
    for (int i = 0; i < 4; i++) {
        int c = (wid * 4 + i) * 64 + lane;
        arow[i] = c >> 3;
        asub[i] = (c & 7) ^ (arow[i] & 7);
    }
#pragma unroll
    for (int i = 0; i < 8; i++) {
        int c = (wid * 8 + i) * 64 + lane;
        brow[i] = c >> 3;
        bsub[i] = (c & 7) ^ (brow[i] & 7);
    }

    for (int w = bid; w < total; w += gridDim.x) {
        const int gm = w / TNT, tn = w - gm * TNT;
        int e = 0;
        while (gm >= spref[e + 1]) e++;
        const int ce = cnt[e], eb = ebase[e];
        const int m0 = (gm - spref[e]) * 128, n0 = tn * 256;

        __syncthreads();
        if (t < 128)
            tokrow[t] = (m0 + t < ce) ? list[eb + m0 + t] : list[eb];
        __syncthreads();

        const unsigned short* aP[4];
        const unsigned short* bP[8];
#pragma unroll
        for (int i = 0; i < 4; i++)
            aP[i] = A + (size_t)tokrow[arow[i]] * K + asub[i] * 8;
#pragma unroll
        for (int i = 0; i < 8; i++)
            bP[i] = Bw + ((size_t)e * N + n0 + brow[i]) * K + bsub[i] * 8;

        f32x4 acc[4][8];
#pragma unroll
        for (int mi = 0; mi < 4; mi++)
#pragma unroll
            for (int ni = 0; ni < 8; ni++) acc[mi][ni] = (f32x4){0, 0, 0, 0};

        for (int k0 = 0; k0 < K; k0 += 64) {
#pragma unroll
            for (int i = 0; i < 4; i++)
                gload16(aP[i] + k0, Asm + (wid * 4 + i) * 512);
#pragma unroll
            for (int i = 0; i < 8; i++)
                gload16(bP[i] + k0, Bsm + (wid * 8 + i) * 512);
            __syncthreads();
#pragma unroll
            for (int kf = 0; kf < 2; kf++) {
                const int phys = ((kf * 4 + lq) ^ (lr & 7)) * 8;
                bf16x8 af[4], bfr[8];
#pragma unroll
                for (int mi = 0; mi < 4; mi++)
                    af[mi] = as_bf(*(const u16x8*)&Asm[(moff + mi * 16 + lr) * 64 + phys]);
#pragma unroll
                for (int ni = 0; ni < 8; ni++)
                    bfr[ni] = as_bf(*(const u16x8*)&Bsm[(noff + ni * 16 + lr) * 64 + phys]);
#pragma unroll
                for (int mi = 0; mi < 4; mi++)
#pragma unroll
                    for (int ni = 0; ni < 8; ni++)
                        acc[mi][ni] = __builtin_amdgcn_mfma_f32_16x16x32_bf16(
                            af[mi], bfr[ni], acc[mi][ni], 0, 0, 0);
            }
            __syncthreads();
        }

#pragma unroll
        for (int mi = 0; mi < 4; mi++) {
#pragma unroll
            for (int r4 = 0; r4 < 4; r4++) {
                const int row = moff + mi * 16 + lq * 4 + r4;
                if (m0 + row < ce) {
                    unsigned short* hp = Hout + (size_t)(eb + m0 + row) * FFD + n0 + noff;
#pragma unroll
                    for (int ni = 0; ni < 8; ni++) {
                        float v = acc[mi][ni][r4];
                        v = v > 0.f ? v : 0.f;
                        hp[ni * 16 + lr] = f2bf(v);
                    }
                }
            }
        }
    }
}

// ---------------------------------------------------------------------------
// GEMM2: 128x256 tile, BK=64, single-buffer 2-barrier (proven ~119us), dense
// A rows from permuted H.
// out[tok,:] = hs[tok,:] + topp[tok]*(Hperm[denserow,:] @ WoT)
// ---------------------------------------------------------------------------
__global__ __launch_bounds__(256, 2) void k_gemm2(
    const unsigned short* __restrict__ A, const unsigned short* __restrict__ Bw,
    const int* __restrict__ list, const int* __restrict__ cnt,
    const float* __restrict__ hs, const float* __restrict__ topp,
    float* __restrict__ out)
{
    constexpr int K   = FFD;
    constexpr int N   = DIM;
    constexpr int TNT = N / 256;                  // 3
    __shared__ unsigned short Asm[128 * 64];      // 16 KB
    __shared__ unsigned short Bsm[256 * 64];      // 32 KB
    __shared__ int tokrow[128];
    __shared__ int spref[9];
    __shared__ int ebase[8];

    const int t = threadIdx.x, lane = t & 63, wid = t >> 6;
    if (t == 0) {
        int p = 0, qq = 0;
        spref[0] = 0;
#pragma unroll
        for (int e = 0; e < 8; e++) {
            ebase[e] = qq; qq += cnt[e];
            p += (cnt[e] + 127) >> 7;
            spref[e + 1] = p;
        }
    }
    __syncthreads();
    const int total = spref[8] * TNT;
    const int moff = (wid >> 1) * 64, noff = (wid & 1) * 128;
    const int lr = lane & 15, lq = lane >> 4;

    const int nwg = gridDim.x;
    const int xcd = blockIdx.x & 7, rr8 = blockIdx.x >> 3;
    const int qd = nwg >> 3, rm = nwg & 7;
    const int bid = (xcd < rm ? xcd * (qd + 1) : rm * (qd + 1) + (xcd - rm) * qd) + rr8;

    int arow[4], asub[4], brow[8], bsub[8];
#pragma unroll
    for (int i = 0; i < 4; i++) {
        int c = (wid * 4 + i) * 64 + lane;
        arow[i] = c >> 3;
        asub[i] = (c & 7) ^ (arow[i] & 7);
    }
#pragma unroll
    for (int i = 0; i < 8; i++) {
        int c = (wid * 8 + i) * 64 + lane;
        brow[i] = c >> 3;
        bsub[i] = (c & 7) ^ (brow[i] & 7);
    }

    for (int w = bid; w < total; w += gridDim.x) {
        const int gm = w / TNT, tn = w - gm * TNT;
        int e = 0;
        while (gm >= spref[e + 1]) e++;
        const int ce = cnt[e], eb = ebase[e];
        const int m0 = (gm - spref[e]) * 128, n0 = tn * 256;

        __syncthreads();
        if (t < 128)
            tokrow[t] = (m0 + t < ce) ? list[eb + m0 + t] : list[eb];
        __syncthreads();

        const unsigned short* aP[4];
        const unsigned short* bP[8];
#pragma unroll
        for (int i = 0; i < 4; i++) {
            const int drow = (m0 + arow[i] < ce) ? (m0 + arow[i]) : (ce - 1);
            aP[i] = A + (size_t)(eb + drow) * K + asub[i] * 8;
        }
#pragma unroll
        for (int i = 0; i < 8; i++)
            bP[i] = Bw + ((size_t)e * N + n0 + brow[i]) * K + bsub[i] * 8;

        f32x4 acc[4][8];
#pragma unroll
        for (int mi = 0; mi < 4; mi++)
#pragma unroll
            for (int ni = 0; ni < 8; ni++) acc[mi][ni] = (f32x4){0, 0, 0, 0};

        for (int k0 = 0; k0 < K; k0 += 64) {
#pragma unroll
            for (int i = 0; i < 4; i++)
                gload16(aP[i] + k0, Asm + (wid * 4 + i) * 512);
#pragma unroll
            for (int i = 0; i < 8; i++)
                gload16(bP[i] + k0, Bsm + (wid * 8 + i) * 512);
            __syncthreads();
#pragma unroll
            for (int kf = 0; kf < 2; kf++) {
                const int phys = ((kf * 4 + lq) ^ (lr & 7)) * 8;
                bf16x8 af[4], bfr[8];
#pragma unroll
                for (int mi = 0; mi < 4; mi++)
                    af[mi] = as_bf(*(const u16x8*)&Asm[(moff + mi * 16 + lr) * 64 + phys]);
#pragma unroll
                for (int ni = 0; ni < 8; ni++)
                    bfr[ni] = as_bf(*(const u16x8*)&Bsm[(noff + ni * 16 + lr) * 64 + phys]);
#pragma unroll
                for (int mi = 0; mi < 4; mi++)
#pragma unroll
                    for (int ni = 0; ni < 8; ni++)
                        acc[mi][ni] = __builtin_amdgcn_mfma_f32_16x16x32_bf16(
                            af[mi], bfr[ni], acc[mi][ni], 0, 0, 0);
            }
            __syncthreads();
        }

#pragma unroll
        for (int mi = 0; mi < 4; mi++) {
#pragma unroll
            for (int r4 = 0; r4 < 4; r4++) {
                const int row = moff + mi * 16 + lq * 4 + r4;
                if (m0 + row < ce) {
                    const int tok = tokrow[row];
                    const float tp = topp[tok];
#pragma unroll
                    for (int ni = 0; ni < 8; ni++) {
                        const size_t idx = (size_t)tok * DIM + n0 + noff + ni * 16 + lr;
                        out[idx] = hs[idx] + tp * acc[mi][ni][r4];
                    }
                }
            }
        }
    }
}

// ---------------------------------------------------------------------------
extern "C" void kernel_launch(void* const* d_in, const int* in_sizes, int n_in,
                              void* d_out, int out_size, void* d_ws, size_t ws_size,
                              hipStream_t stream)
{
    const float* hs  = (const float*)d_in[0];
    const float* lnw = (const float*)d_in[1];
    const float* rw  = (const float*)d_in[2];
    const float* wi  = (const float*)d_in[3];
    const float* wo  = (const float*)d_in[4];

    float* out        = (float*)d_out;
    float* out_logits = out + (size_t)N_TOK * DIM;
    float* out_eidx   = out_logits + (size_t)N_TOK * NEXP;

    char* ws = (char*)d_ws;
    size_t off = 0;
    int*   cnt     = (int*)(ws + off);         off += 256;
    int*   list    = (int*)(ws + off);         off += (size_t)N_TOK * 4;
    float* topp    = (float*)(ws + off);       off += (size_t)N_TOK * 4;
    int*   eidx    = (int*)(ws + off);         off += (size_t)N_TOK * 4;
    int*   blkhist = (int*)(ws + off);         off += 4096;
    int*   base    = (int*)(ws + off);         off += 4096;
    unsigned short* xn  = (unsigned short*)(ws + off); off += (size_t)N_TOK * DIM * 2;
    unsigned short* Hb  = (unsigned short*)(ws + off); off += (size_t)N_TOK * FFD * 2;
    unsigned short* wob = (unsigned short*)(ws + off);

    // wi^T (bf16 [e][F][D]) lives in d_out's first 37.75 MB: dead before
    // GEMM2's epilogue writes `out`.
    unsigned short* wib = (unsigned short*)d_out;

    k_setup<<<13312, 256, 0, stream>>>(wi, wib, wo, wob, hs, lnw, rw,
                                       out_logits, out_eidx, topp, eidx, xn);
    k_hist<<<64, 256, 0, stream>>>(eidx, blkhist);
    k_prefix<<<1, 512, 0, stream>>>(blkhist, base, cnt);
    k_scatter<<<64, 256, 0, stream>>>(eidx, base, list);
    k_gemm1<<<1632, 256, 0, stream>>>(xn, wib, list, cnt, Hb);
    k_gemm2<<<408, 256, 0, stream>>>(Hb, wob, list, cnt, hs, topp, out);
}